// Round 22
// baseline (72.669 us; speedup 1.0000x reference)
//
#include <hip/hip_runtime.h>

// Problem constants (fixed by setup_inputs)
#define B_    4
#define C_    128
#define CQ_   16
#define N_    4096
#define KVBLK 64

typedef short          s16x8 __attribute__((ext_vector_type(8)));
typedef unsigned short u16x4 __attribute__((ext_vector_type(4)));
typedef unsigned int   u32x4 __attribute__((ext_vector_type(4)));
typedef float          f32x4 __attribute__((ext_vector_type(4)));
typedef unsigned short u16;
typedef unsigned int   u32;

__device__ __forceinline__ u16 f2bf(float f) {
    unsigned int u = __builtin_bit_cast(unsigned int, f);
    u += 0x7fffu + ((u >> 16) & 1u);           // round-to-nearest-even
    return (u16)(u >> 16);
}
__device__ __forceinline__ float bf2f(u16 h) {
    unsigned int u = ((unsigned int)h) << 16;
    return __builtin_bit_cast(float, u);
}
__device__ __forceinline__ s16x8 ld8bf(const u16* p) {
    return *reinterpret_cast<const s16x8*>(p);
}
__device__ __forceinline__ u32 cvtpk_bf16(float lo, float hi) {
    u32 r;
    asm("v_cvt_pk_bf16_f32 %0, %1, %2" : "=v"(r) : "v"(lo), "v"(hi));
    return r;
}
__device__ __forceinline__ void gld_lds16(const u16* src, u16* lds) {
    __builtin_amdgcn_global_load_lds(
        (const __attribute__((address_space(1))) void*)src,
        (__attribute__((address_space(3))) void*)lds, 16, 0, 0);
}

// kv bit-permutation: PV consumes V at LDS col kv' = slot (ss,g,j); the S-row
// that lands in that slot (own-lane pack, no shuffles) is
// r = 16*(2ss + (j>>2)) + 4g + (j&3).  pi: kv'->r is the bit shuffle
// r5=b5, r4=b2, r3:2=b4:3, r1:0=b1:0.  Projection stores V column r at
// position invpi(r) so attn's linear staging delivers slot-order V.
__device__ __forceinline__ int invpi64(int r) {
    return (r & 0x23) | ((r & 0x10) >> 2) | ((r & 0x0C) << 1);
}

// ---------------------------------------------------------------------------
// Fused projections, one launch (z=0: q&k, z=1..2: v slices of 64 channels).
// Round-22 rewrite: each thread accumulates the FULL c=128 range for a few
// output channels — removes the 4-chunk LDS partial-reduce round-trip and
// cuts x traffic 40MB -> 24MB (x read 3x instead of 5x).
//   z=0: 4 groups = {q ch0-7, q ch8-15, k ch0-7, k ch8-15}, 8 ch/thread.
//   z=1,2: 64-channel V slice, 4 groups x 16 ch/thread; weights staged
//   LDS-transposed [c][64] (32KB) -> wave-broadcast b128 reads.
// Q pre-scaled by log2(e); V stored kv-permuted (invpi within 64-blocks).
// Accumulation order over c is sequential (was 4-chunk tree) — absmax may
// move a little within budget.
// ---------------------------------------------------------------------------
__global__ __launch_bounds__(256) void proj_all_kernel(
    const float* __restrict__ x,
    const float* __restrict__ wq, const float* __restrict__ bq,
    const float* __restrict__ wk, const float* __restrict__ bk,
    const float* __restrict__ wv, const float* __restrict__ bv,
    u16* __restrict__ Qb, u16* __restrict__ Kb, u16* __restrict__ Vb)
{
    __shared__ float smem[8192];    // 32 KB max (V slice weights)
    const int tid = threadIdx.x;
    const int b   = blockIdx.y;
    const int nl  = tid & 63;
    const int n   = blockIdx.x * 64 + nl;
    const int grp = tid >> 6;       // 0..3 (one wave per group)
    const float* xp = x + ((size_t)b * C_) * N_ + n;

    if (blockIdx.z == 0) {
        // ---------------- q & k projection ----------------
        float* wqs = smem;          // [c][16] 2048
        float* wks = smem + 2048;   // [c][16] 2048
        for (int i = tid; i < CQ_ * C_; i += 256) {
            const int j = i & 15, c = i >> 4;          // transpose store
            wqs[i] = wq[j * C_ + c];
            wks[i] = wk[j * C_ + c];
        }
        __syncthreads();

        const bool isk = (grp >= 2);
        const int  j0  = (grp & 1) * 8;
        const float* ws = isk ? wks : wqs;

        float acc[8];
#pragma unroll
        for (int j = 0; j < 8; ++j) acc[j] = 0.f;
        for (int c = 0; c < C_; ++c) {
            const float xv = xp[(size_t)c * N_];
#pragma unroll
            for (int j = 0; j < 8; ++j)                // contiguous -> b128 broadcast
                acc[j] = fmaf(ws[c * 16 + j0 + j], xv, acc[j]);
        }

        const float* bias = isk ? bk : bq;
        const float scale = isk ? 1.0f : 1.4426950408889634f;  // log2(e) into Q
        alignas(16) u16 hi[8], lo[8];
#pragma unroll
        for (int j = 0; j < 8; ++j) {
            const float v = (acc[j] + bias[j0 + j]) * scale;
            const u16 h = f2bf(v);
            hi[j] = h;
            lo[j] = f2bf(v - bf2f(h));                 // lo residual (scaled value)
        }
        u16* dst = (isk ? Kb : Qb) + ((size_t)(b * N_ + n)) * 32 + j0;
        *reinterpret_cast<uint4*>(dst)      = *reinterpret_cast<const uint4*>(hi);
        *reinterpret_cast<uint4*>(dst + 16) = *reinterpret_cast<const uint4*>(lo);
    } else {
        // ---------------- v projection (64 channels), kv-permuted store ----
        const int cv0 = (blockIdx.z - 1) * 64;
        float* wvs = smem;          // [c][64] 8192 floats = 32KB
        for (int i = tid; i < 64 * C_; i += 256) {
            const int j = i & 63, c = i >> 6;          // transpose store
            wvs[i] = wv[(cv0 + j) * C_ + c];
        }
        __syncthreads();

        const int j0 = grp * 16;
        float acc[16];
#pragma unroll
        for (int j = 0; j < 16; ++j) acc[j] = 0.f;
        for (int c = 0; c < C_; ++c) {
            const float xv = xp[(size_t)c * N_];
#pragma unroll
            for (int j = 0; j < 16; ++j)               // contiguous -> b128 broadcast
                acc[j] = fmaf(wvs[c * 64 + j0 + j], xv, acc[j]);
        }

        const int nlp = invpi64(nl);   // permuted position within the 64-block
#pragma unroll
        for (int j = 0; j < 16; ++j) {
            const float v = acc[j] + bv[cv0 + j0 + j];
            Vb[((size_t)(b * C_ + cv0 + j0 + j)) * N_ + blockIdx.x * 64 + nlp] = f2bf(v);
        }
    }
}

// ---------------------------------------------------------------------------
// Split-KV fused attention, LDS double-buffered DMA pipeline.
// (byte-identical to passing round 21: 256 thr, 4 waves x 32 q,
// launch_bounds(256,3), NSPLIT=4, XCD swizzle, no-relayout via kv-permuted V,
// ones-MFMA denominator, exp2f, no setprio.)
// ---------------------------------------------------------------------------
template<int NSPLIT>
__global__ __launch_bounds__(256, 3) void attn_split_kernel(
    const u16* __restrict__ Qb, const u16* __restrict__ Kb, const u16* __restrict__ Vb,
    u16* __restrict__ Opart, float* __restrict__ Lpart)
{
    constexpr int MPER = N_ / NSPLIT;
    constexpr int NT   = MPER / KVBLK;

    __shared__ __align__(16) u16 Kt[2][KVBLK * 32];    // [kv][32d] swz (kv&3)<<4
    __shared__ __align__(16) u16 Vt[2][C_ * KVBLK];    // [c][64kv'] swz (c&7)<<4

    const int tid  = threadIdx.x;
    const int lane = tid & 63;
    const int l16  = lane & 15;
    const int g    = lane >> 4;       // 0..3
    const int wave = tid >> 6;        // 0..3 — owns q-cols n0+32*wave..+31

    // ---- XCD-aware swizzle (1-D grid of 32*B_*NSPLIT blocks) ----
    const int L    = blockIdx.x;
    const int grp  = (L & 7) + 8 * (L >> 8);   // (b,s) group: same XCD for all j
    const int j    = (L >> 3) & 31;
    const int b    = grp & 3;
    const int s    = grp >> 2;
    const int n0   = j * 128;
    const int ms   = s * MPER;

    // Q B-fragments for the wave's two 16-col groups (log2e-prescaled)
    const int qn = n0 + wave * 32 + l16;
    const s16x8 qf0 = ld8bf(Qb + ((size_t)(b * N_ + qn)) * 32 + 8 * g);
    const s16x8 qf1 = ld8bf(Qb + ((size_t)(b * N_ + qn + 16)) * 32 + 8 * g);

    // ---- staging source addresses (pre-swizzled global, linear LDS) ----
    const int kv_s   = tid >> 2;
    const int kcol_s = ((tid & 3) * 16) ^ ((kv_s & 3) << 4);
    const u16* ksrc0 = Kb + ((size_t)b * N_ + kv_s) * 32 + (kcol_s >> 1);
    // V: c_i = i*32 + vc_s; (c_i & 7) == (vc_s & 7) for all i, so the
    // pre-swizzled column is i-invariant: one base + i * 32*N_ offsets.
    const int vc_s   = tid >> 3;
    const int vcol_s = ((tid & 7) * 16) ^ ((vc_s & 7) << 4);
    const u16* vsrcB = Vb + ((size_t)(b * C_ + vc_s)) * N_ + (vcol_s >> 1);

    // ---- per-lane LDS read offsets (u16 units; loop-invariant) ----
    const int kswz  = (l16 & 3) << 4;
    const int vswz  = (l16 & 7) << 4;
    const int koff1 = l16 * 32 + (((16 * (g & 1)) ^ kswz) >> 1);
    const int koff2 = l16 * 32 + (((32 + 16 * g) ^ kswz) >> 1);   // g<2 only
    const int voffA = l16 * 64 + (((16 * g) ^ vswz) >> 1);        // kv' 8g..8g+7
    const int voffB = l16 * 64 + (((64 + 16 * g) ^ vswz) >> 1);   // kv' 32+8g.. (full XOR)

    const s16x8 ones = { 0x3F80, 0x3F80, 0x3F80, 0x3F80,
                         0x3F80, 0x3F80, 0x3F80, 0x3F80 };  // bf16 1.0 x8

    f32x4 acc0[8], acc1[8];
#pragma unroll
    for (int cg = 0; cg < 8; ++cg) { acc0[cg] = {}; acc1[cg] = {}; }
    f32x4 accl0 = {}, accl1 = {};

    // Own-lane pack: S rows {16*2ss+4g+i, 16*(2ss+1)+4g+i} -> B-frag slots
    // 8g..8g+7 of slice ss (V side pre-permuted by pi to match).
    auto packpf = [&](const float (&p)[4][4], int ss) -> s16x8 {
        u32x4 w;
        w[0] = cvtpk_bf16(p[2 * ss][0],     p[2 * ss][1]);
        w[1] = cvtpk_bf16(p[2 * ss][2],     p[2 * ss][3]);
        w[2] = cvtpk_bf16(p[2 * ss + 1][0], p[2 * ss + 1][1]);
        w[3] = cvtpk_bf16(p[2 * ss + 1][2], p[2 * ss + 1][3]);
        return __builtin_bit_cast(s16x8, w);
    };

    auto body = [&](int t, int buf) {
        // ---- stage tile t+1 into the other buffer (fire-and-forget DMA) ----
        if (t + 1 < NT) {
            const int mn = ms + (t + 1) * KVBLK;
            gld_lds16(ksrc0 + (size_t)mn * 32, &Kt[buf ^ 1][wave * 512]);
#pragma unroll
            for (int i = 0; i < 4; ++i)
                gld_lds16(vsrcB + (size_t)i * 32 * N_ + mn,
                          &Vt[buf ^ 1][i * 2048 + wave * 512]);
        }
        const u16* ktb = &Kt[buf][0];
        const u16* vtb = &Vt[buf][0];

        // ---- S^T = K . Q^T for both col-groups (K-frags reused) ----
        f32x4 s0[4], s1[4];
#pragma unroll
        for (int mg = 0; mg < 4; ++mg) {
            const s16x8 kf1 = ld8bf(ktb + koff1 + mg * 512);
            s16x8 kf2 = {};
            if (g < 2) kf2 = ld8bf(ktb + koff2 + mg * 512);
            f32x4 z0 = {}, z1 = {};
            z0 = __builtin_amdgcn_mfma_f32_16x16x32_bf16(kf1, qf0, z0, 0, 0, 0);
            z0 = __builtin_amdgcn_mfma_f32_16x16x32_bf16(kf2, qf0, z0, 0, 0, 0);
            z1 = __builtin_amdgcn_mfma_f32_16x16x32_bf16(kf1, qf1, z1, 0, 0, 0);
            z1 = __builtin_amdgcn_mfma_f32_16x16x32_bf16(kf2, qf1, z1, 0, 0, 0);
            s0[mg] = z0; s1[mg] = z1;
        }

        // ---- P = 2^(S^T); own-lane pack to B-frags (NO shuffles) ----
        s16x8 pf0a, pf0b, pf1a, pf1b;
        {
            float p[4][4];
#pragma unroll
            for (int mg = 0; mg < 4; ++mg)
#pragma unroll
                for (int i = 0; i < 4; ++i) p[mg][i] = exp2f(s0[mg][i]);
            pf0a = packpf(p, 0); pf0b = packpf(p, 1);
        }
        {
            float p[4][4];
#pragma unroll
            for (int mg = 0; mg < 4; ++mg)
#pragma unroll
                for (int i = 0; i < 4; ++i) p[mg][i] = exp2f(s1[mg][i]);
            pf1a = packpf(p, 0); pf1b = packpf(p, 1);
        }

        // ---- O^T += V^T . P^T ; l via ones-row MFMA ----
        accl0 = __builtin_amdgcn_mfma_f32_16x16x32_bf16(ones, pf0a, accl0, 0, 0, 0);
        accl0 = __builtin_amdgcn_mfma_f32_16x16x32_bf16(ones, pf0b, accl0, 0, 0, 0);
        accl1 = __builtin_amdgcn_mfma_f32_16x16x32_bf16(ones, pf1a, accl1, 0, 0, 0);
        accl1 = __builtin_amdgcn_mfma_f32_16x16x32_bf16(ones, pf1b, accl1, 0, 0, 0);
#pragma unroll
        for (int cg = 0; cg < 8; ++cg) {
            const s16x8 vfa = ld8bf(vtb + voffA + cg * 1024);
            acc0[cg] = __builtin_amdgcn_mfma_f32_16x16x32_bf16(vfa, pf0a, acc0[cg], 0, 0, 0);
            acc1[cg] = __builtin_amdgcn_mfma_f32_16x16x32_bf16(vfa, pf1a, acc1[cg], 0, 0, 0);
            const s16x8 vfb = ld8bf(vtb + voffB + cg * 1024);
            acc0[cg] = __builtin_amdgcn_mfma_f32_16x16x32_bf16(vfb, pf0b, acc0[cg], 0, 0, 0);
            acc1[cg] = __builtin_amdgcn_mfma_f32_16x16x32_bf16(vfb, pf1b, acc1[cg], 0, 0, 0);
        }

        // ---- drain DMA for tile t+1, flip ----
        asm volatile("s_waitcnt vmcnt(0)" ::: "memory");
        __syncthreads();
    };

    // ---- prologue: stage tile 0 into buf 0 ----
    gld_lds16(ksrc0 + (size_t)ms * 32, &Kt[0][wave * 512]);
#pragma unroll
    for (int i = 0; i < 4; ++i)
        gld_lds16(vsrcB + (size_t)i * 32 * N_ + ms, &Vt[0][i * 2048 + wave * 512]);
    asm volatile("s_waitcnt vmcnt(0)" ::: "memory");
    __syncthreads();

    for (int tt = 0; tt < NT / 2; ++tt) {
        body(2 * tt, 0);         // literal buffer index -> base+imm ds addrs
        body(2 * tt + 1, 1);
    }

    // ---- epilogue: store partial l and unnormalized partial O (bf16) ----
    const size_t sb = (size_t)(s * B_ + b);
    if (lane < 16) {
        Lpart[sb * N_ + n0 + wave * 32 + l16]      = accl0[0];
        Lpart[sb * N_ + n0 + wave * 32 + 16 + l16] = accl1[0];
    }

    const int na = n0 + wave * 32 + l16;
#pragma unroll
    for (int cg = 0; cg < 8; ++cg) {
#pragma unroll
        for (int i = 0; i < 4; ++i) {
            const int c = 16 * cg + 4 * g + i;
            Opart[(sb * C_ + c) * N_ + na]      = f2bf(acc0[cg][i]);
            Opart[(sb * C_ + c) * N_ + na + 16] = f2bf(acc1[cg][i]);
        }
    }
}

// ---------------------------------------------------------------------------
// Combine splits: out = gamma * (sum_s Opart) / (sum_s Lpart) + x.
// ---------------------------------------------------------------------------
template<int NSPLIT>
__global__ __launch_bounds__(256) void reduce_kernel(
    const u16* __restrict__ Opart, const float* __restrict__ Lpart,
    const float* __restrict__ x, const float* __restrict__ gamma,
    float* __restrict__ out)
{
    const int t  = blockIdx.x * 256 + threadIdx.x;      // 524288 threads
    const size_t e0 = (size_t)t * 4;                    // < B*C*N = 2^21
    const int n = (int)(e0 & (N_ - 1));
    const int c = (int)((e0 >> 12) & (C_ - 1));
    const int b = (int)(e0 >> 19);

    float o0 = 0.f, o1 = 0.f, o2 = 0.f, o3 = 0.f;
    f32x4 l = {};
#pragma unroll
    for (int s = 0; s < NSPLIT; ++s) {
        const size_t sb = (size_t)(s * B_ + b);
        const u16x4 ov = *reinterpret_cast<const u16x4*>(Opart + (sb * C_ + c) * N_ + n);
        const f32x4 lv = *reinterpret_cast<const f32x4*>(Lpart + sb * N_ + n);
        o0 += bf2f(ov[0]); o1 += bf2f(ov[1]); o2 += bf2f(ov[2]); o3 += bf2f(ov[3]);
        l += lv;
    }
    const float gm = gamma[0];
    const f32x4 xv = *reinterpret_cast<const f32x4*>(x + e0);
    f32x4 r;
    r[0] = gm * o0 / l[0] + xv[0];
    r[1] = gm * o1 / l[1] + xv[1];
    r[2] = gm * o2 / l[2] + xv[2];
    r[3] = gm * o3 / l[3] + xv[3];
    *reinterpret_cast<f32x4*>(out + e0) = r;
}

// ---------------------------------------------------------------------------
extern "C" void kernel_launch(void* const* d_in, const int* in_sizes, int n_in,
                              void* d_out, int out_size, void* d_ws, size_t ws_size,
                              hipStream_t stream)
{
    const float* x     = (const float*)d_in[0];
    const float* wq    = (const float*)d_in[1];
    const float* bq    = (const float*)d_in[2];
    const float* wk    = (const float*)d_in[3];
    const float* bk    = (const float*)d_in[4];
    const float* wv    = (const float*)d_in[5];
    const float* bv    = (const float*)d_in[6];
    const float* gamma = (const float*)d_in[7];
    float* out = (float*)d_out;

    // ws layout: Qb 1MB | Kb 1MB | Vb 4MB | Opart 16MB | Lpart 256KB (~22.5MB)
    u16* Qb = (u16*)d_ws;                               // (B,N,32)  [hi|lo], log2e-scaled
    u16* Kb = Qb + (size_t)B_ * N_ * 32;                // (B,N,32)  [hi|lo]
    u16* Vb = Kb + (size_t)B_ * N_ * 32;                // (B,C,N)   bf16, kv-permuted
    u16* Opart = Vb + (size_t)B_ * C_ * N_;             // (4,B,C,N) bf16
    float* Lpart = (float*)(Opart + (size_t)4 * B_ * C_ * N_);  // (4,B,N)

    proj_all_kernel<<<dim3(N_ / 64, B_, 3), 256, 0, stream>>>(
        x, wq, bq, wk, bk, wv, bv, Qb, Kb, Vb);
    attn_split_kernel<4><<<dim3((N_ / 128) * B_ * 4), 256, 0, stream>>>(
        Qb, Kb, Vb, Opart, Lpart);
    reduce_kernel<4><<<(B_ * C_ * N_ / 4) / 256, 256, 0, stream>>>(
        Opart, Lpart, x, gamma, out);
}

// Round 23
// 70.999 us; speedup vs baseline: 1.0235x; 1.0235x over previous
//
#include <hip/hip_runtime.h>

// Problem constants (fixed by setup_inputs)
#define B_    4
#define C_    128
#define CQ_   16
#define N_    4096
#define KVBLK 64

typedef short          s16x8 __attribute__((ext_vector_type(8)));
typedef unsigned short u16x4 __attribute__((ext_vector_type(4)));
typedef unsigned int   u32x4 __attribute__((ext_vector_type(4)));
typedef float          f32x4 __attribute__((ext_vector_type(4)));
typedef unsigned short u16;
typedef unsigned int   u32;

__device__ __forceinline__ u16 f2bf(float f) {
    unsigned int u = __builtin_bit_cast(unsigned int, f);
    u += 0x7fffu + ((u >> 16) & 1u);           // round-to-nearest-even
    return (u16)(u >> 16);
}
__device__ __forceinline__ float bf2f(u16 h) {
    unsigned int u = ((unsigned int)h) << 16;
    return __builtin_bit_cast(float, u);
}
__device__ __forceinline__ s16x8 ld8bf(const u16* p) {
    return *reinterpret_cast<const s16x8*>(p);
}
__device__ __forceinline__ u32 cvtpk_bf16(float lo, float hi) {
    u32 r;
    asm("v_cvt_pk_bf16_f32 %0, %1, %2" : "=v"(r) : "v"(lo), "v"(hi));
    return r;
}
__device__ __forceinline__ void gld_lds16(const u16* src, u16* lds) {
    __builtin_amdgcn_global_load_lds(
        (const __attribute__((address_space(1))) void*)src,
        (__attribute__((address_space(3))) void*)lds, 16, 0, 0);
}

// kv bit-permutation: PV consumes V at LDS col kv' = slot (ss,g,j); the S-row
// that lands in that slot (own-lane pack, no shuffles) is
// r = 16*(2ss + (j>>2)) + 4g + (j&3).  pi: kv'->r is the bit shuffle
// r5=b5, r4=b2, r3:2=b4:3, r1:0=b1:0.  Projection stores V column r at
// position invpi(r) so attn's linear staging delivers slot-order V.
__device__ __forceinline__ int invpi64(int r) {
    return (r & 0x23) | ((r & 0x10) >> 2) | ((r & 0x0C) << 1);
}

// ---------------------------------------------------------------------------
// Fused projections, one launch (z=0: q&k, z=1..4: v chunk of 32 channels).
// (round-15 form: weights staged LDS-transposed [c][j] so the unrolled
// j-loop reads contiguous b128; per-thread FMA order fixed. r22's
// full-c-range rewrite was null-to-negative and is reverted.)
// Q pre-scaled by log2(e); V stored kv-permuted (invpi within each 64-block).
// ---------------------------------------------------------------------------
__global__ __launch_bounds__(256) void proj_all_kernel(
    const float* __restrict__ x,
    const float* __restrict__ wq, const float* __restrict__ bq,
    const float* __restrict__ wk, const float* __restrict__ bk,
    const float* __restrict__ wv, const float* __restrict__ bv,
    u16* __restrict__ Qb, u16* __restrict__ Kb, u16* __restrict__ Vb)
{
    __shared__ float smem[12800];   // 51.2 KB, carved per-branch
    const int tid = threadIdx.x;
    const int b   = blockIdx.y;
    const int nl  = tid & 63;
    const int n   = blockIdx.x * 64 + nl;
    const int ch  = tid >> 6;
    const float* xp = x + ((size_t)b * C_) * N_ + n;

    if (blockIdx.z == 0) {
        // ---------------- q & k projection ----------------
        float* wqs = smem;               // [c][j] 2048
        float* wks = smem + 2048;        // [c][j] 2048
        float (*part)[4][64][17] = (float (*)[4][64][17])(smem + 4096);
        for (int i = tid; i < CQ_ * C_; i += 256) {
            const int j = i & 15, c = i >> 4;          // dst = c*16 + j
            wqs[i] = wq[j * C_ + c];                   // transpose store
            wks[i] = wk[j * C_ + c];
        }
        __syncthreads();

        float qa[CQ_], ka[CQ_];
#pragma unroll
        for (int j = 0; j < CQ_; ++j) { qa[j] = 0.f; ka[j] = 0.f; }
        const int c0 = ch * 32;
        for (int c = c0; c < c0 + 32; ++c) {
            const float xv = xp[(size_t)c * N_];
#pragma unroll
            for (int j = 0; j < CQ_; ++j) {            // contiguous -> b128 reads
                qa[j] = fmaf(wqs[c * 16 + j], xv, qa[j]);
                ka[j] = fmaf(wks[c * 16 + j], xv, ka[j]);
            }
        }
#pragma unroll
        for (int j = 0; j < CQ_; ++j) { part[0][ch][nl][j] = qa[j]; part[1][ch][nl][j] = ka[j]; }
        __syncthreads();

        if (tid < 128) {
            const int which = tid >> 6;        // 0 -> q, 1 -> k
            const int n2 = tid & 63;
            const float* bias = which ? bk : bq;
            const float scale = which ? 1.0f : 1.4426950408889634f;  // log2(e) into Q
            alignas(16) u16 row[32];
#pragma unroll
            for (int j = 0; j < CQ_; ++j) {
                float v = (part[which][0][n2][j] + part[which][1][n2][j]
                         + part[which][2][n2][j] + part[which][3][n2][j] + bias[j]) * scale;
                u16 h = f2bf(v);
                row[j]       = h;
                row[CQ_ + j] = f2bf(v - bf2f(h));   // lo residual (of scaled value)
            }
            u16* dst = (which ? Kb : Qb) + ((size_t)(b * N_ + blockIdx.x * 64 + n2)) * 32;
#pragma unroll
            for (int i = 0; i < 4; ++i)
                reinterpret_cast<uint4*>(dst)[i] = reinterpret_cast<const uint4*>(row)[i];
        }
    } else {
        // ---------------- v projection (32 channels), kv-permuted store ----
        const int cv0 = (blockIdx.z - 1) * 32;
        float* wvs = smem;               // [c][j] 4096
        float (*part)[64][33] = (float (*)[64][33])(smem + 4096);
        for (int i = tid; i < 32 * C_; i += 256) {
            const int j = i & 31, c = i >> 5;          // dst = c*32 + j
            wvs[i] = wv[(cv0 + j) * C_ + c];           // transpose store
        }
        __syncthreads();

        float acc[32];
#pragma unroll
        for (int j = 0; j < 32; ++j) acc[j] = 0.f;
        const int c0 = ch * 32;
        for (int c = c0; c < c0 + 32; ++c) {
            const float xv = xp[(size_t)c * N_];
#pragma unroll
            for (int j = 0; j < 32; ++j)               // contiguous -> b128 reads
                acc[j] = fmaf(wvs[c * 32 + j], xv, acc[j]);
        }
#pragma unroll
        for (int j = 0; j < 32; ++j) part[ch][nl][j] = acc[j];
        __syncthreads();

        const int jq  = tid >> 6;
        const int nlp = invpi64(nl);     // permuted position within the 64-block
#pragma unroll
        for (int jj = 0; jj < 8; ++jj) {
            const int j = jq * 8 + jj;
            float v = part[0][nl][j] + part[1][nl][j] + part[2][nl][j] + part[3][nl][j]
                    + bv[cv0 + j];
            Vb[((size_t)(b * C_ + cv0 + j)) * N_ + blockIdx.x * 64 + nlp] = f2bf(v);
        }
    }
}

// ---------------------------------------------------------------------------
// Split-KV fused attention, LDS double-buffered DMA pipeline.
// (session-best round-21 form: 256 thr, 4 waves x 32 q, launch_bounds(256,3),
// NSPLIT=4, XCD swizzle, no-relayout via kv-permuted V, ones-MFMA
// denominator, exp2f, no setprio.)
// ---------------------------------------------------------------------------
template<int NSPLIT>
__global__ __launch_bounds__(256, 3) void attn_split_kernel(
    const u16* __restrict__ Qb, const u16* __restrict__ Kb, const u16* __restrict__ Vb,
    u16* __restrict__ Opart, float* __restrict__ Lpart)
{
    constexpr int MPER = N_ / NSPLIT;
    constexpr int NT   = MPER / KVBLK;

    __shared__ __align__(16) u16 Kt[2][KVBLK * 32];    // [kv][32d] swz (kv&3)<<4
    __shared__ __align__(16) u16 Vt[2][C_ * KVBLK];    // [c][64kv'] swz (c&7)<<4

    const int tid  = threadIdx.x;
    const int lane = tid & 63;
    const int l16  = lane & 15;
    const int g    = lane >> 4;       // 0..3
    const int wave = tid >> 6;        // 0..3 — owns q-cols n0+32*wave..+31

    // ---- XCD-aware swizzle (1-D grid of 32*B_*NSPLIT blocks) ----
    const int L    = blockIdx.x;
    const int grp  = (L & 7) + 8 * (L >> 8);   // (b,s) group: same XCD for all j
    const int j    = (L >> 3) & 31;
    const int b    = grp & 3;
    const int s    = grp >> 2;
    const int n0   = j * 128;
    const int ms   = s * MPER;

    // Q B-fragments for the wave's two 16-col groups (log2e-prescaled)
    const int qn = n0 + wave * 32 + l16;
    const s16x8 qf0 = ld8bf(Qb + ((size_t)(b * N_ + qn)) * 32 + 8 * g);
    const s16x8 qf1 = ld8bf(Qb + ((size_t)(b * N_ + qn + 16)) * 32 + 8 * g);

    // ---- staging source addresses (pre-swizzled global, linear LDS) ----
    const int kv_s   = tid >> 2;
    const int kcol_s = ((tid & 3) * 16) ^ ((kv_s & 3) << 4);
    const u16* ksrc0 = Kb + ((size_t)b * N_ + kv_s) * 32 + (kcol_s >> 1);
    // V: c_i = i*32 + vc_s; (c_i & 7) == (vc_s & 7) for all i, so the
    // pre-swizzled column is i-invariant: one base + i * 32*N_ offsets.
    const int vc_s   = tid >> 3;
    const int vcol_s = ((tid & 7) * 16) ^ ((vc_s & 7) << 4);
    const u16* vsrcB = Vb + ((size_t)(b * C_ + vc_s)) * N_ + (vcol_s >> 1);

    // ---- per-lane LDS read offsets (u16 units; loop-invariant) ----
    const int kswz  = (l16 & 3) << 4;
    const int vswz  = (l16 & 7) << 4;
    const int koff1 = l16 * 32 + (((16 * (g & 1)) ^ kswz) >> 1);
    const int koff2 = l16 * 32 + (((32 + 16 * g) ^ kswz) >> 1);   // g<2 only
    const int voffA = l16 * 64 + (((16 * g) ^ vswz) >> 1);        // kv' 8g..8g+7
    const int voffB = l16 * 64 + (((64 + 16 * g) ^ vswz) >> 1);   // kv' 32+8g.. (full XOR)

    const s16x8 ones = { 0x3F80, 0x3F80, 0x3F80, 0x3F80,
                         0x3F80, 0x3F80, 0x3F80, 0x3F80 };  // bf16 1.0 x8

    f32x4 acc0[8], acc1[8];
#pragma unroll
    for (int cg = 0; cg < 8; ++cg) { acc0[cg] = {}; acc1[cg] = {}; }
    f32x4 accl0 = {}, accl1 = {};

    // Own-lane pack: S rows {16*2ss+4g+i, 16*(2ss+1)+4g+i} -> B-frag slots
    // 8g..8g+7 of slice ss (V side pre-permuted by pi to match).
    auto packpf = [&](const float (&p)[4][4], int ss) -> s16x8 {
        u32x4 w;
        w[0] = cvtpk_bf16(p[2 * ss][0],     p[2 * ss][1]);
        w[1] = cvtpk_bf16(p[2 * ss][2],     p[2 * ss][3]);
        w[2] = cvtpk_bf16(p[2 * ss + 1][0], p[2 * ss + 1][1]);
        w[3] = cvtpk_bf16(p[2 * ss + 1][2], p[2 * ss + 1][3]);
        return __builtin_bit_cast(s16x8, w);
    };

    auto body = [&](int t, int buf) {
        // ---- stage tile t+1 into the other buffer (fire-and-forget DMA) ----
        if (t + 1 < NT) {
            const int mn = ms + (t + 1) * KVBLK;
            gld_lds16(ksrc0 + (size_t)mn * 32, &Kt[buf ^ 1][wave * 512]);
#pragma unroll
            for (int i = 0; i < 4; ++i)
                gld_lds16(vsrcB + (size_t)i * 32 * N_ + mn,
                          &Vt[buf ^ 1][i * 2048 + wave * 512]);
        }
        const u16* ktb = &Kt[buf][0];
        const u16* vtb = &Vt[buf][0];

        // ---- S^T = K . Q^T for both col-groups (K-frags reused) ----
        f32x4 s0[4], s1[4];
#pragma unroll
        for (int mg = 0; mg < 4; ++mg) {
            const s16x8 kf1 = ld8bf(ktb + koff1 + mg * 512);
            s16x8 kf2 = {};
            if (g < 2) kf2 = ld8bf(ktb + koff2 + mg * 512);
            f32x4 z0 = {}, z1 = {};
            z0 = __builtin_amdgcn_mfma_f32_16x16x32_bf16(kf1, qf0, z0, 0, 0, 0);
            z0 = __builtin_amdgcn_mfma_f32_16x16x32_bf16(kf2, qf0, z0, 0, 0, 0);
            z1 = __builtin_amdgcn_mfma_f32_16x16x32_bf16(kf1, qf1, z1, 0, 0, 0);
            z1 = __builtin_amdgcn_mfma_f32_16x16x32_bf16(kf2, qf1, z1, 0, 0, 0);
            s0[mg] = z0; s1[mg] = z1;
        }

        // ---- P = 2^(S^T); own-lane pack to B-frags (NO shuffles) ----
        s16x8 pf0a, pf0b, pf1a, pf1b;
        {
            float p[4][4];
#pragma unroll
            for (int mg = 0; mg < 4; ++mg)
#pragma unroll
                for (int i = 0; i < 4; ++i) p[mg][i] = exp2f(s0[mg][i]);
            pf0a = packpf(p, 0); pf0b = packpf(p, 1);
        }
        {
            float p[4][4];
#pragma unroll
            for (int mg = 0; mg < 4; ++mg)
#pragma unroll
                for (int i = 0; i < 4; ++i) p[mg][i] = exp2f(s1[mg][i]);
            pf1a = packpf(p, 0); pf1b = packpf(p, 1);
        }

        // ---- O^T += V^T . P^T ; l via ones-row MFMA ----
        accl0 = __builtin_amdgcn_mfma_f32_16x16x32_bf16(ones, pf0a, accl0, 0, 0, 0);
        accl0 = __builtin_amdgcn_mfma_f32_16x16x32_bf16(ones, pf0b, accl0, 0, 0, 0);
        accl1 = __builtin_amdgcn_mfma_f32_16x16x32_bf16(ones, pf1a, accl1, 0, 0, 0);
        accl1 = __builtin_amdgcn_mfma_f32_16x16x32_bf16(ones, pf1b, accl1, 0, 0, 0);
#pragma unroll
        for (int cg = 0; cg < 8; ++cg) {
            const s16x8 vfa = ld8bf(vtb + voffA + cg * 1024);
            acc0[cg] = __builtin_amdgcn_mfma_f32_16x16x32_bf16(vfa, pf0a, acc0[cg], 0, 0, 0);
            acc1[cg] = __builtin_amdgcn_mfma_f32_16x16x32_bf16(vfa, pf1a, acc1[cg], 0, 0, 0);
            const s16x8 vfb = ld8bf(vtb + voffB + cg * 1024);
            acc0[cg] = __builtin_amdgcn_mfma_f32_16x16x32_bf16(vfb, pf0b, acc0[cg], 0, 0, 0);
            acc1[cg] = __builtin_amdgcn_mfma_f32_16x16x32_bf16(vfb, pf1b, acc1[cg], 0, 0, 0);
        }

        // ---- drain DMA for tile t+1, flip ----
        asm volatile("s_waitcnt vmcnt(0)" ::: "memory");
        __syncthreads();
    };

    // ---- prologue: stage tile 0 into buf 0 ----
    gld_lds16(ksrc0 + (size_t)ms * 32, &Kt[0][wave * 512]);
#pragma unroll
    for (int i = 0; i < 4; ++i)
        gld_lds16(vsrcB + (size_t)i * 32 * N_ + ms, &Vt[0][i * 2048 + wave * 512]);
    asm volatile("s_waitcnt vmcnt(0)" ::: "memory");
    __syncthreads();

    for (int tt = 0; tt < NT / 2; ++tt) {
        body(2 * tt, 0);         // literal buffer index -> base+imm ds addrs
        body(2 * tt + 1, 1);
    }

    // ---- epilogue: store partial l and unnormalized partial O (bf16) ----
    const size_t sb = (size_t)(s * B_ + b);
    if (lane < 16) {
        Lpart[sb * N_ + n0 + wave * 32 + l16]      = accl0[0];
        Lpart[sb * N_ + n0 + wave * 32 + 16 + l16] = accl1[0];
    }

    const int na = n0 + wave * 32 + l16;
#pragma unroll
    for (int cg = 0; cg < 8; ++cg) {
#pragma unroll
        for (int i = 0; i < 4; ++i) {
            const int c = 16 * cg + 4 * g + i;
            Opart[(sb * C_ + c) * N_ + na]      = f2bf(acc0[cg][i]);
            Opart[(sb * C_ + c) * N_ + na + 16] = f2bf(acc1[cg][i]);
        }
    }
}

// ---------------------------------------------------------------------------
// Combine splits: out = gamma * (sum_s Opart) / (sum_s Lpart) + x.
// ---------------------------------------------------------------------------
template<int NSPLIT>
__global__ __launch_bounds__(256) void reduce_kernel(
    const u16* __restrict__ Opart, const float* __restrict__ Lpart,
    const float* __restrict__ x, const float* __restrict__ gamma,
    float* __restrict__ out)
{
    const int t  = blockIdx.x * 256 + threadIdx.x;      // 524288 threads
    const size_t e0 = (size_t)t * 4;                    // < B*C*N = 2^21
    const int n = (int)(e0 & (N_ - 1));
    const int c = (int)((e0 >> 12) & (C_ - 1));
    const int b = (int)(e0 >> 19);

    float o0 = 0.f, o1 = 0.f, o2 = 0.f, o3 = 0.f;
    f32x4 l = {};
#pragma unroll
    for (int s = 0; s < NSPLIT; ++s) {
        const size_t sb = (size_t)(s * B_ + b);
        const u16x4 ov = *reinterpret_cast<const u16x4*>(Opart + (sb * C_ + c) * N_ + n);
        const f32x4 lv = *reinterpret_cast<const f32x4*>(Lpart + sb * N_ + n);
        o0 += bf2f(ov[0]); o1 += bf2f(ov[1]); o2 += bf2f(ov[2]); o3 += bf2f(ov[3]);
        l += lv;
    }
    const float gm = gamma[0];
    const f32x4 xv = *reinterpret_cast<const f32x4*>(x + e0);
    f32x4 r;
    r[0] = gm * o0 / l[0] + xv[0];
    r[1] = gm * o1 / l[1] + xv[1];
    r[2] = gm * o2 / l[2] + xv[2];
    r[3] = gm * o3 / l[3] + xv[3];
    *reinterpret_cast<f32x4*>(out + e0) = r;
}

// ---------------------------------------------------------------------------
extern "C" void kernel_launch(void* const* d_in, const int* in_sizes, int n_in,
                              void* d_out, int out_size, void* d_ws, size_t ws_size,
                              hipStream_t stream)
{
    const float* x     = (const float*)d_in[0];
    const float* wq    = (const float*)d_in[1];
    const float* bq    = (const float*)d_in[2];
    const float* wk    = (const float*)d_in[3];
    const float* bk    = (const float*)d_in[4];
    const float* wv    = (const float*)d_in[5];
    const float* bv    = (const float*)d_in[6];
    const float* gamma = (const float*)d_in[7];
    float* out = (float*)d_out;

    // ws layout: Qb 1MB | Kb 1MB | Vb 4MB | Opart 16MB | Lpart 256KB (~22.5MB)
    u16* Qb = (u16*)d_ws;                               // (B,N,32)  [hi|lo], log2e-scaled
    u16* Kb = Qb + (size_t)B_ * N_ * 32;                // (B,N,32)  [hi|lo]
    u16* Vb = Kb + (size_t)B_ * N_ * 32;                // (B,C,N)   bf16, kv-permuted
    u16* Opart = Vb + (size_t)B_ * C_ * N_;             // (4,B,C,N) bf16
    float* Lpart = (float*)(Opart + (size_t)4 * B_ * C_ * N_);  // (4,B,N)

    proj_all_kernel<<<dim3(N_ / 64, B_, 5), 256, 0, stream>>>(
        x, wq, bq, wk, bk, wv, bv, Qb, Kb, Vb);
    attn_split_kernel<4><<<dim3((N_ / 128) * B_ * 4), 256, 0, stream>>>(
        Qb, Kb, Vb, Opart, Lpart);
    reduce_kernel<4><<<(B_ * C_ * N_ / 4) / 256, 256, 0, stream>>>(
        Opart, Lpart, x, gamma, out);
}